// Round 8
// baseline (289.422 us; speedup 1.0000x reference)
//
#include <hip/hip_runtime.h>
#include <hip/hip_bf16.h>

// Problem: out[b,q,d] = softmax(e[b,q,:]) @ sent[b,:,d]
// B=64, L2=1024, L1=1024, D=768, fp32 in/out.
// Softmax via shift-invariance: out = (exp(e) @ sent) * (1/rowsum(exp(e)))
//
// Round-8:
//  pass1 prep: MERGED transpose_cast + exp_rows (both BW-bound; one launch).
//  pass2 gemm2 v3: 256x256xBK64 dbuf, DEEP-SLACK quadrant schedule.
//    r4/r5 plateau diagnosis: (M x K)-phases first-read 75% of a staged tile
//    at P0 => no pipeline slack. v3 phases are (M-half x N-half, full K);
//    stage units {A-alpha, B-N0, A-beta, B-N1} are first consumed 2-3 phases
//    after issue => counted vmcnt(4) checkpoints (never 0), pure-dbuf staging
//    (no intra-tile anti-deps) => only 3 barriers/tile (P0/P1/P3 ends).
// Workspace: sT @0 (100,663,296 B), expE (134,217,728 B), rsInv (262,144 B).
// Fallback (small ws): transpose + round-3 fused ring (verified).

#define B_  64
#define L1_ 1024
#define L2_ 1024
#define D_  768

typedef __attribute__((ext_vector_type(8))) short short8;
typedef __attribute__((ext_vector_type(4))) float f32x4;
typedef __attribute__((ext_vector_type(8))) unsigned short ushort8;
typedef __attribute__((ext_vector_type(4))) unsigned short ushort4v;

static __device__ __forceinline__ unsigned short f2bf(float x) {
  union { float f; unsigned int u; } c; c.f = x;
  unsigned int r = c.u + 0x7FFF + ((c.u >> 16) & 1);  // RNE
  return (unsigned short)(r >> 16);
}

#define GLOAD(gp, lp) \
  __builtin_amdgcn_global_load_lds((const __attribute__((address_space(1))) char*)(gp), \
                                   (__attribute__((address_space(3))) char*)(lp), 16, 0, 0)

// ---------------- merged prep: transpose_cast blocks + exp_rows blocks -----
// blocks [0, 12288): sent[b][l][d] f32 -> sT[b][d][l] bf16 (64x64 LDS tiles)
// blocks [12288, 16384): e f32 -> expE bf16 rows + rsInv = 1/rowsum(exp)
#define TC_BLOCKS (12 * 16 * 64)     // 12288
__global__ __launch_bounds__(256) void prep_kernel(const float* __restrict__ sent,
                                                   const float* __restrict__ e,
                                                   unsigned short* __restrict__ sT,
                                                   unsigned short* __restrict__ expE,
                                                   float* __restrict__ rsInv) {
  __shared__ unsigned short tile[64][66];
  const int bid = blockIdx.x;
  const int t   = threadIdx.x;
  if (bid < TC_BLOCKS) {
    const int b  = bid / 192;          // 12*16 blocks per batch
    const int r2 = bid % 192;
    const int l0 = (r2 / 12) << 6;
    const int d0 = (r2 % 12) << 6;
    const float* sp = sent + ((size_t)b * L1_ + l0) * D_ + d0;
    const int c4 = (t & 15) << 2;
    const int r0 = t >> 4;
#pragma unroll
    for (int p = 0; p < 4; ++p) {
      const int r = r0 + (p << 4);
      float4 v = *reinterpret_cast<const float4*>(sp + (size_t)r * D_ + c4);
      tile[r][c4 + 0] = f2bf(v.x);
      tile[r][c4 + 1] = f2bf(v.y);
      tile[r][c4 + 2] = f2bf(v.z);
      tile[r][c4 + 3] = f2bf(v.w);
    }
    __syncthreads();
    unsigned short* op = sT + ((size_t)b * D_ + d0) * L1_ + l0;
    const int l8  = (t & 7) << 3;
    const int dd0 = t >> 3;
#pragma unroll
    for (int p = 0; p < 2; ++p) {
      const int d = dd0 + (p << 5);
      ushort8 w;
#pragma unroll
      for (int j = 0; j < 8; ++j) w[j] = tile[l8 + j][d];
      *reinterpret_cast<ushort8*>(op + (size_t)d * L1_ + l8) = w;
    }
  } else {
    const int lane = t & 63;
    const int wv   = t >> 6;
    const int rowb = (bid - TC_BLOCKS) << 4;
#pragma unroll
    for (int i = 0; i < 4; ++i) {
      const int row = rowb + (i << 2) + wv;
      const float* rp = e + (size_t)row * L1_;
      unsigned short* op = expE + (size_t)row * L1_;
      float s = 0.f;
#pragma unroll
      for (int j = 0; j < 4; ++j) {
        float4 v = *reinterpret_cast<const float4*>(rp + j * 256 + lane * 4);
        float e0 = __expf(v.x), e1 = __expf(v.y), e2 = __expf(v.z), e3 = __expf(v.w);
        s += (e0 + e1) + (e2 + e3);
        ushort4v o;
        o[0] = f2bf(e0); o[1] = f2bf(e1); o[2] = f2bf(e2); o[3] = f2bf(e3);
        *reinterpret_cast<ushort4v*>(op + j * 256 + lane * 4) = o;
      }
#pragma unroll
      for (int dd = 1; dd < 64; dd <<= 1) s += __shfl_xor(s, dd);
      if (lane == 0) rsInv[row] = 1.0f / s;
    }
  }
}

// ---------------- gemm2 v3: 256x256 BK=64, deep-slack quadrant phases ------
#define BM2 256
#define BN2 256
#define BK2 64
#define NT2   (L1_ / BK2)             // 16
#define MT2   (L2_ / BM2)             // 4
#define NTL2  (D_ / BN2)              // 3
#define NWG2  (B_ * MT2 * NTL2)       // 768 (divisible by 8)

// Stage units (2 gloads/thread = 16 KiB each), LDS dest linear, src slot
// pre-swizzled (sslot): A-alpha rows {0-63,128-191} (RR=0); A-beta (RR=1).
#define SAU(T, BUF, RR) do { const int _tt = (T) & (NT2 - 1); \
    GLOAD(Asrc2 + (size_t)(RR) * 64 * L1_ + _tt * BK2, \
          &As2[BUF][((RR) * 64 + w * 8) * BK2]); \
    GLOAD(Asrc2 + (size_t)((RR) + 2) * 64 * L1_ + _tt * BK2, \
          &As2[BUF][(((RR) + 2) * 64 + w * 8) * BK2]); \
  } while (0)
// B-N-half NH: rows {s*64 + NH*32 + 0..31 | s=0..3} (the cols read at NH).
#define SBN(T, BUF, NH) do { const int _tt = (T) & (NT2 - 1); \
    { const int _b0 = ((w) >> 2) * 64 + (NH) * 32 + ((w) & 3) * 8; \
      GLOAD(BsrcS + (size_t)_b0 * L1_ + _tt * BK2, &Bs2[BUF][_b0 * BK2]); } \
    { const int _g1 = 8 + w; \
      const int _b1 = (_g1 >> 2) * 64 + (NH) * 32 + (_g1 & 3) * 8; \
      GLOAD(BsrcS + (size_t)_b1 * L1_ + _tt * BK2, &Bs2[BUF][_b1 * BK2]); } \
  } while (0)

// checkpoint: counted drain + publish (barrier). Never vmcnt(0) in the loop.
#define CKPT do { \
    asm volatile("s_waitcnt vmcnt(4)" ::: "memory"); \
    __builtin_amdgcn_s_barrier(); \
  } while (0)

// one phase = quadrant (RH, NH), full K=64. RDB: load b_ (else reuse held).
// Own ds_reads drained by lgkm(0) BEFORE any barrier (no cross-wave read/DMA
// race). sched_barrier(0) after lgkm per rule: stop MFMA hoisting past it.
#define PHASE3(RB, RH, NH, RDB, PRE, POST) do { \
    PRE \
    if (RDB) { \
      _Pragma("unroll") \
      for (int jj = 0; jj < 2; ++jj) { \
        const int rb_ = wn * 64 + (NH) * 32 + jj * 16 + l15; \
        _Pragma("unroll") \
        for (int kk = 0; kk < 2; ++kk) \
          b_[jj][kk] = *reinterpret_cast<const short8*>( \
              &Bs2[RB][rb_ * BK2 + (((kk * 4 + ksl) ^ (l15 & 7)) << 3)]); \
      } \
    } \
    short8 a_[4][2]; \
    _Pragma("unroll") \
    for (int ii = 0; ii < 4; ++ii) { \
      const int ra_ = wm * 128 + ((RH) * 4 + ii) * 16 + l15; \
      _Pragma("unroll") \
      for (int kk = 0; kk < 2; ++kk) \
        a_[ii][kk] = *reinterpret_cast<const short8*>( \
            &As2[RB][ra_ * BK2 + (((kk * 4 + ksl) ^ (l15 & 7)) << 3)]); \
    } \
    asm volatile("s_waitcnt lgkmcnt(0)" ::: "memory"); \
    __builtin_amdgcn_sched_barrier(0); \
    __builtin_amdgcn_s_setprio(1); \
    _Pragma("unroll") \
    for (int kk = 0; kk < 2; ++kk) \
      _Pragma("unroll") \
      for (int ii = 0; ii < 4; ++ii) \
        _Pragma("unroll") \
        for (int jj = 0; jj < 2; ++jj) \
          acc[(RH) * 4 + ii][(NH) * 2 + jj] = __builtin_amdgcn_mfma_f32_16x16x32_bf16( \
              a_[ii][kk], b_[jj][kk], acc[(RH) * 4 + ii][(NH) * 2 + jj], 0, 0, 0); \
    __builtin_amdgcn_s_setprio(0); \
    POST \
  } while (0)

// one K-tile = 4 quadrant phases, order (0,0)(1,0)(1,1)(0,1); b_ held across
// adjacent same-NH pairs. Stage (into RB^1): P0 Aa, P1 BN0, P2 Ab, P3 BN1.
// First-reads next tile: Aa@P0, BN0@P0, Ab@P1, BN1@P2 =>
//  CKPT@P0-end drains Ab(t)   [outstanding Ab,BN1,Aa' = 6 -> 4]
//  CKPT@P1-end drains BN1(t)  [BN1,Aa',BN0' = 6 -> 4]
//  (none @P2-end)
//  CKPT@P3-end drains Aa,BN0(t+1) [8 -> 4]
#define TILE3(T, RB) do { \
    PHASE3(RB, 0, 0, 1, SAU((T) + 1, (RB) ^ 1, 0);, CKPT;); \
    PHASE3(RB, 1, 0, 0, SBN((T) + 1, (RB) ^ 1, 0);, CKPT;); \
    PHASE3(RB, 1, 1, 1, SAU((T) + 1, (RB) ^ 1, 1);, ;); \
    PHASE3(RB, 0, 1, 0, SBN((T) + 1, (RB) ^ 1, 1);, CKPT;); \
  } while (0)

__global__ __launch_bounds__(512, 2) void gemm2_kernel(const unsigned short* __restrict__ expE,
                                                       const unsigned short* __restrict__ sT,
                                                       const float* __restrict__ rsInv,
                                                       float* __restrict__ out) {
  __shared__ __align__(16) unsigned short As2[2][BM2 * BK2];  // 64 KiB
  __shared__ __align__(16) unsigned short Bs2[2][BN2 * BK2];  // 64 KiB
  __shared__ float sArr[BM2];                                 // 1 KiB

  const int orig = blockIdx.x;
  const int wgid = (orig & 7) * (NWG2 / 8) + (orig >> 3);
  const int b    = wgid / (MT2 * NTL2);
  const int rem  = wgid % (MT2 * NTL2);
  const int m0   = (rem / NTL2) * BM2;
  const int n0   = (rem % NTL2) * BN2;

  const int t    = threadIdx.x;
  const int lane = t & 63;
  const int w    = t >> 6;           // 0..7
  const int wm   = w >> 2;           // 0..1 (M): rows wm*128..+127
  const int wn   = w & 3;            // 0..3 (N): cols wn*64..+63
  const int l15  = lane & 15;
  const int ksl  = lane >> 4;        // frag k-slot 0..3

  // staging: lane covers row (+lane>>3) slot (lane&7); phys slot holds
  // logical slot (lane&7)^(row&7) -> source pre-swizzle.
  const int sslot = (lane & 7) ^ (lane >> 3);
  const unsigned short* Asrc2 = expE + ((size_t)b * L2_ + m0 + w * 8 + (lane >> 3)) * L1_ + sslot * 8;
  const unsigned short* BsrcS = sT   + ((size_t)b * D_  + n0 + (lane >> 3)) * L1_ + sslot * 8;

  f32x4 acc[8][4] = {};
  short8 b_[2][2];

  // prologue: rsInv->sArr; tile0 fully staged into buf0; full drain (once).
  if (t < BM2) sArr[t] = rsInv[(size_t)b * L2_ + m0 + t];
  SAU(0, 0, 0); SAU(0, 0, 1); SBN(0, 0, 0); SBN(0, 0, 1);
  asm volatile("s_waitcnt vmcnt(0) lgkmcnt(0)" ::: "memory");
  __builtin_amdgcn_s_barrier();

#pragma unroll 1
  for (int kt = 0; kt < NT2; kt += 2) {
    TILE3(kt,     0);
    TILE3(kt + 1, 1);
  }
  asm volatile("s_waitcnt vmcnt(0)" ::: "memory");  // drain tail garbage stages

  // epilogue: C/D layout col=lane&15, row=(lane>>4)*4+reg; scale by 1/rowsum
  const int rbase = (lane >> 4) << 2;
  float* Cb = out + ((size_t)b * L2_ + m0 + wm * 128) * D_ + n0 + wn * 64;
#pragma unroll
  for (int i = 0; i < 8; ++i) {
    float inv[4];
#pragma unroll
    for (int r = 0; r < 4; ++r)
      inv[r] = sArr[wm * 128 + i * 16 + rbase + r];
#pragma unroll
    for (int jj = 0; jj < 4; ++jj)
#pragma unroll
      for (int r = 0; r < 4; ++r)
        Cb[(size_t)(i * 16 + rbase + r) * D_ + jj * 16 + l15] = acc[i][jj][r] * inv[r];
  }
}

// ================= fallback path (small ws): verified round-3 kernels ======
__global__ __launch_bounds__(256) void transpose_cast_kernel(const float* __restrict__ sent,
                                                             unsigned short* __restrict__ sT) {
  __shared__ unsigned short tile[64][66];
  const int b  = blockIdx.z;
  const int l0 = blockIdx.y << 6;
  const int d0 = blockIdx.x << 6;
  const int t  = threadIdx.x;
  const float* sp = sent + ((size_t)b * L1_ + l0) * D_ + d0;
  const int c4 = (t & 15) << 2;
  const int r0 = t >> 4;
#pragma unroll
  for (int p = 0; p < 4; ++p) {
    const int r = r0 + (p << 4);
    float4 v = *reinterpret_cast<const float4*>(sp + (size_t)r * D_ + c4);
    tile[r][c4 + 0] = f2bf(v.x);
    tile[r][c4 + 1] = f2bf(v.y);
    tile[r][c4 + 2] = f2bf(v.z);
    tile[r][c4 + 3] = f2bf(v.w);
  }
  __syncthreads();
  unsigned short* op = sT + ((size_t)b * D_ + d0) * L1_ + l0;
  const int l8  = (t & 7) << 3;
  const int dd0 = t >> 3;
#pragma unroll
  for (int p = 0; p < 2; ++p) {
    const int d = dd0 + (p << 5);
    ushort8 w;
#pragma unroll
    for (int j = 0; j < 8; ++j) w[j] = tile[l8 + j][d];
    *reinterpret_cast<ushort8*>(op + (size_t)d * L1_ + l8) = w;
  }
}

#define BM 128
#define BN 256
#define BK 32
#define NT    (L1_ / BK)
#define NTILE (D_ / BN)
#define MTILE (L2_ / BM)
#define NWG   (NTILE * MTILE * B_)

#define SW(r) ((((r) >> 2) ^ (r)) & 3)

#define LOADA(T) do { const int _ta = (T) & (NT - 1);                                        \
    aregs[0] = *reinterpret_cast<const float4*>(Ae + (size_t)rA * L1_ + _ta * BK + cA);      \
    aregs[1] = *reinterpret_cast<const float4*>(Ae + (size_t)rA * L1_ + _ta * BK + cA + 4);  \
  } while (0)

#define EXPWRITE(T) do { if ((T) < NT) {                                        \
    unsigned short* Ad_ = &As[(T) & 1][0];                                      \
    float ex_[8];                                                               \
    ex_[0] = __expf(aregs[0].x); ex_[1] = __expf(aregs[0].y);                   \
    ex_[2] = __expf(aregs[0].z); ex_[3] = __expf(aregs[0].w);                   \
    ex_[4] = __expf(aregs[1].x); ex_[5] = __expf(aregs[1].y);                   \
    ex_[6] = __expf(aregs[1].z); ex_[7] = __expf(aregs[1].w);                   \
    psum += ((ex_[0] + ex_[1]) + (ex_[2] + ex_[3]))                             \
          + ((ex_[4] + ex_[5]) + (ex_[6] + ex_[7]));                            \
    ushort8 w0_;                                                                \
    _Pragma("unroll")                                                           \
    for (int q_ = 0; q_ < 8; ++q_) w0_[q_] = f2bf(ex_[q_]);                     \
    *reinterpret_cast<ushort8*>(&Ad_[rA * BK + aslot * 8]) = w0_;               \
  } } while (0)

#define SBF(T) do { if ((T) < NT) {                                             \
    GLOAD(Bb + (size_t)rB0 * L1_ + (T) * BK + sB0, &Bs[(T) & 1][(w * 32) * BK]);      \
    GLOAD(Bb + (size_t)rB1 * L1_ + (T) * BK + sB1, &Bs[(T) & 1][(w * 32 + 16) * BK]); \
  } } while (0)

__global__ __launch_bounds__(512, 2) void gemm_fused_kernel(const float* __restrict__ e,
                                                            const unsigned short* __restrict__ sT,
                                                            float* __restrict__ out) {
  __shared__ __align__(16) unsigned short As[2][BM * BK];
  __shared__ __align__(16) unsigned short Bs[2][BN * BK];
  __shared__ float sArr[BM];

  const int orig = blockIdx.x;
  const int wgid = (orig & 7) * (NWG / 8) + (orig >> 3);
  const int b    = wgid / (NTILE * MTILE);
  const int rem  = wgid % (NTILE * MTILE);
  const int m0   = (rem / NTILE) * BM;
  const int n0   = (rem % NTILE) * BN;

  const int t    = threadIdx.x;
  const int lane = t & 63;
  const int w    = t >> 6;
  const int wm   = w >> 2;
  const int wn   = w & 3;
  const int l15  = lane & 15;
  const int ksl  = lane >> 4;
  const int rA   = w * 16 + (lane >> 2);
  const int cA   = (lane & 3) * 8;
  const int aslot = (lane & 3) ^ SW(rA);
  const int rB0  = w * 32 + (lane >> 2);
  const int rB1  = rB0 + 16;
  const int sB0  = ((lane & 3) ^ SW(rB0)) * 8;
  const int sB1  = ((lane & 3) ^ SW(rB1)) * 8;

  const float*          Ae = e  + ((size_t)b * L2_ + m0) * L1_;
  const unsigned short* Bb = sT + ((size_t)b * D_  + n0) * L1_;

  f32x4 acc[4][4] = {};
  float4 aregs[2];
  float psum = 0.f;

  LOADA(0);
  SBF(0);
  EXPWRITE(0);
  LOADA(1);
  asm volatile("s_waitcnt vmcnt(2) lgkmcnt(0)" ::: "memory");
  __builtin_amdgcn_s_barrier();
  __builtin_amdgcn_sched_barrier(0);

  for (int kt = 0; kt < NT; ++kt) {
    SBF(kt + 1);
    EXPWRITE(kt + 1);
    LOADA(kt + 2);

    const unsigned short* Apt = As[kt & 1];
    const unsigned short* Bpt = Bs[kt & 1];
    short8 a[4], bb[4];
    __builtin_amdgcn_s_setprio(1);
#pragma unroll
    for (int i = 0; i < 4; ++i) {
      const int ra = wm * 64 + i * 16 + l15;
      a[i] = *reinterpret_cast<const short8*>(&Apt[ra * BK + ((ksl ^ SW(ra)) << 3)]);
      const int rb = wn * 64 + i * 16 + l15;
      bb[i] = *reinterpret_cast<const short8*>(&Bpt[rb * BK + ((ksl ^ SW(rb)) << 3)]);
    }
#pragma unroll
    for (int i = 0; i < 4; ++i)
#pragma unroll
      for (int jn = 0; jn < 4; ++jn)
        acc[i][jn] = __builtin_amdgcn_mfma_f32_16x16x32_bf16(a[i], bb[jn], acc[i][jn], 0, 0, 0);
    __builtin_amdgcn_s_setprio(0);

    if (kt < NT - 1) {
      asm volatile("s_waitcnt vmcnt(2) lgkmcnt(0)" ::: "memory");
      __builtin_amdgcn_s_barrier();
      __builtin_amdgcn_sched_barrier(0);
    }
  }

  psum += __shfl_xor(psum, 1);
  psum += __shfl_xor(psum, 2);
  if ((lane & 3) == 0) sArr[rA] = psum;
  __syncthreads();

  const int rbase = (lane >> 4) << 2;
  float* Cb = out + ((size_t)b * L2_ + m0 + wm * 64) * D_ + n0 + wn * 64;
#pragma unroll
  for (int i = 0; i < 4; ++i) {
    float inv[4];
#pragma unroll
    for (int r = 0; r < 4; ++r)
      inv[r] = 1.0f / sArr[wm * 64 + i * 16 + rbase + r];
#pragma unroll
    for (int jn = 0; jn < 4; ++jn)
#pragma unroll
      for (int r = 0; r < 4; ++r)
        Cb[(size_t)(i * 16 + rbase + r) * D_ + jn * 16 + l15] = acc[i][jn][r] * inv[r];
  }
}

extern "C" void kernel_launch(void* const* d_in, const int* in_sizes, int n_in,
                              void* d_out, int out_size, void* d_ws, size_t ws_size,
                              hipStream_t stream) {
  const float* sent = (const float*)d_in[0];
  const float* e    = (const float*)d_in[1];
  float* out = (float*)d_out;

  const size_t ST_BYTES   = (size_t)B_ * D_ * L1_ * 2;        // 100,663,296
  const size_t EXPE_BYTES = (size_t)B_ * L2_ * L1_ * 2;       // 134,217,728
  const size_t RS_BYTES   = (size_t)B_ * L2_ * 4;             // 262,144

  unsigned short* sT = (unsigned short*)d_ws;

  if (ws_size >= ST_BYTES + EXPE_BYTES + RS_BYTES) {
    unsigned short* expE  = (unsigned short*)((char*)d_ws + ST_BYTES);
    float*          rsInv = (float*)((char*)d_ws + ST_BYTES + EXPE_BYTES);
    prep_kernel<<<dim3(TC_BLOCKS + B_ * L2_ / 16), 256, 0, stream>>>(sent, e, sT, expE, rsInv);
    gemm2_kernel<<<dim3(NWG2), 512, 0, stream>>>(expE, sT, rsInv, out);
  } else {
    transpose_cast_kernel<<<dim3(D_ / 64, L1_ / 64, B_), 256, 0, stream>>>(sent, sT);
    gemm_fused_kernel<<<dim3(NWG), 512, 0, stream>>>(e, sT, out);
  }
}